// Round 1
// 1350.426 us; speedup vs baseline: 3.1261x; 3.1261x over previous
//
#include <hip/hip_runtime.h>
#include <hip/hip_bf16.h>

typedef unsigned short u16;
typedef unsigned int u32;
typedef __attribute__((ext_vector_type(8))) short short8;   // 8 bf16 (4 VGPRs)
typedef __attribute__((ext_vector_type(4))) float f32x4;    // MFMA acc

#define DEVFN static __device__ __forceinline__

DEVFN float b2f(u16 u) { return __uint_as_float(((u32)u) << 16); }
DEVFN void up2(u32 w, float& a, float& b) {
  a = __uint_as_float(w << 16);
  b = __uint_as_float(w & 0xffff0000u);
}
DEVFN u16 f2b(float f) {
  u32 u = __float_as_uint(f);
  return (u16)((u + 0x7fffu + ((u >> 16) & 1u)) >> 16);
}

// Detect whether buffer holds packed bf16 (vs fp32). Block-uniform, deterministic.
DEVFN bool probe_bf16(const void* x) {
  const u32* p = (const u32*)x;
  int cnt = 0;
  for (int i = 0; i < 64; i++) {
    u32 lo = p[i] & 0xffffu;
    u32 e = (lo >> 7) & 0xffu;
    cnt += ((lo == 0u) || (e >= 97u && e <= 132u)) ? 1 : 0;
  }
  return cnt >= 48;
}

// dtype-dual global accessors
DEVFN float ld1(const void* p, size_t i, bool bf) {
  return bf ? b2f(((const u16*)p)[i]) : ((const float*)p)[i];
}
DEVFN void st1(void* p, size_t i, bool bf, float v) {
  if (bf) ((u16*)p)[i] = f2b(v); else ((float*)p)[i] = v;
}
DEVFN void ld2(const void* p, size_t i, bool bf, float& a, float& b) {
  if (bf) up2(*(const u32*)((const u16*)p + i), a, b);
  else { float2 t = *(const float2*)((const float*)p + i); a = t.x; b = t.y; }
}
DEVFN void ld8(const void* p, size_t i, bool bf, float* f) {
  if (bf) {
    uint4 q = *(const uint4*)((const u16*)p + i);
    up2(q.x, f[0], f[1]); up2(q.y, f[2], f[3]);
    up2(q.z, f[4], f[5]); up2(q.w, f[6], f[7]);
  } else {
    float4 t0 = *(const float4*)((const float*)p + i);
    float4 t1 = *(const float4*)((const float*)p + i + 4);
    f[0]=t0.x; f[1]=t0.y; f[2]=t0.z; f[3]=t0.w;
    f[4]=t1.x; f[5]=t1.y; f[6]=t1.z; f[7]=t1.w;
  }
}
DEVFN void st2(void* p, size_t i, bool bf, float a, float b) {
  if (bf) *(u32*)((u16*)p + i) = (u32)f2b(a) | ((u32)f2b(b) << 16);
  else *(float2*)((float*)p + i) = make_float2(a, b);
}

DEVFN short8 lds16(const u16* p) { return *reinterpret_cast<const short8*>(p); }
DEVFN short8 gld16(const u16* p) { return *reinterpret_cast<const short8*>(p); }

// tanh-approx GELU; |err| <= ~3e-3 vs exact erf-GELU
DEVFN float gelu_t(float x) {
  const float z = x * (0.7978845608f + 0.0356774081f * x * x);
  const float e = __expf(2.f * z);
  const float t = 1.f - 2.f / (e + 1.f);
  return 0.5f * x * (1.f + t);
}

// Config: B=8 H=64 W=512 C=192 NH=6 HD=32 WH=4 WW=8 SH=2 SW=4
// N=32 tokens/window, 8192 windows total. Tokens = 262144.

// ---------------------------------------------------------------------------
// Weight transpose into d_ws (bf16 always):
//   ws[0 .. 147455]        = w1t[768][192],   w1t[j][k]   = w1[k][j]
//   ws[147456 .. 294911]   = w2t[192][768],   w2t[c][h]   = w2[h][c]
//   ws[294912 .. 405503]   = wqkvT[576][192], row r = hp*192 + sel*64 + hh*32 + d
//                            -> original col j = sel*192 + (2hp+hh)*32 + d
//   ws[405504 .. 442367]   = wprojT[192][192], wprojT[n][k] = wproj[k][n]
// ---------------------------------------------------------------------------
__global__ void transpose_weights(const void* __restrict__ w1,
                                  const void* __restrict__ w2,
                                  const void* __restrict__ wqkv,
                                  const void* __restrict__ wproj,
                                  u16* __restrict__ ws)
{
  const bool bf = probe_bf16(w1);
  const int idx = blockIdx.x * 256 + threadIdx.x;   // 0 .. 442367
  if (idx < 147456) {
    const int j = idx / 192, k = idx - 192 * j;
    ws[idx] = f2b(ld1(w1, (size_t)k * 768 + j, bf));
  } else if (idx < 294912) {
    const int i2 = idx - 147456;
    const int c = i2 / 768, h = i2 - 768 * c;
    ws[idx] = f2b(ld1(w2, (size_t)h * 192 + c, bf));
  } else if (idx < 405504) {
    const int i2 = idx - 294912;
    const int r = i2 / 192, k = i2 - 192 * r;      // r in [0,576)
    const int hp = r / 192, cc = r - 192 * hp;
    const int sel = cc >> 6, hh = (cc >> 5) & 1, d = cc & 31;
    const int j = sel * 192 + (2 * hp + hh) * 32 + d;
    ws[idx] = f2b(ld1(wqkv, (size_t)k * 576 + j, bf));
  } else {
    const int i2 = idx - 405504;
    const int n = i2 / 192, k = i2 - 192 * n;
    ws[idx] = f2b(ld1(wproj, (size_t)k * 192 + n, bf));
  }
}

// ---------------------------------------------------------------------------
// Kernel A (MFMA rewrite): one window (32 tokens) per block, 4 waves.
// MFMA 16x16x32 bf16. A-frag: A[m=lane&15][k=quad*8+j] (8 contiguous k).
// B-frag: B[k=quad*8+j][n=lane&15] from [n][k] memory. D[row=quad*4+r][col].
//
// Per head-pair hp (3 iters):
//   QKV GEMM  (M=32,N=192,K=192) -> Qh/Kh [tok][dim], VT [dim][tok]
//   S^T = K @ Q^T (per head): softmax over keys is 8 regs + shfl_xor(16,32)
//   O^T = V^T @ P^T : D rows = dims (contiguous per lane) -> b64 stores to Ou
// Then proj GEMM (M=32,N=192,K=192) + bias + residual -> out.
// Static LDS = 45,056 B -> 3 blocks/CU.
// ---------------------------------------------------------------------------
__launch_bounds__(256, 3)
__global__ void swin_attn_mfma(
    const void* __restrict__ x, const void* __restrict__ g1, const void* __restrict__ be1,
    const u16* __restrict__ wqkvT, const void* __restrict__ bqkv,
    const u16* __restrict__ wprojT, const void* __restrict__ bproj,
    const void* __restrict__ btab, void* __restrict__ out)
{
  __shared__ __align__(16) u16 Xn[32][200];     // LN1 out [tok][cin]   12800 B
  __shared__ __align__(16) u16 Qh[32][72];      // [tok][hh*32+d]        4608 B
  __shared__ __align__(16) u16 Kh[32][72];      //                       4608 B
  __shared__ __align__(16) u16 VT[64][40];      // [hh*32+d][tok]        5120 B
  __shared__ __align__(16) u16 Pl[2][32][40];   // [hh][query][key]      5120 B
  __shared__ __align__(16) u16 Ou[32][200];     // attn out [tok][chan] 12800 B

  const bool bf = probe_bf16(x);
  const int tid = threadIdx.x;
  const int wid = blockIdx.x;
  const int b   = wid >> 10;
  const int wli = wid & 1023;
  const int whi = wli >> 6;
  const int wwi = wli & 63;

  auto gtok = [&](int n) -> int {
    const int r = n >> 3, c = n & 7;
    const int ho = (whi * 4 + r + 2) & 63;
    const int wo = (wwi * 8 + c + 4) & 511;
    return (b << 15) + ho * 512 + wo;
  };

  // ---- LN1 -> Xn (8 threads per token, 24 chans each) ----
  {
    const int n = tid >> 3, g = tid & 7;
    const int c0 = g * 24;
    const size_t base = (size_t)gtok(n) * 192 + c0;
    float v[24];
    ld8(x, base, bf, v); ld8(x, base + 8, bf, v + 8); ld8(x, base + 16, bf, v + 16);
    float s = 0.f, ss = 0.f;
#pragma unroll
    for (int i = 0; i < 24; i++) { s += v[i]; ss += v[i] * v[i]; }
#pragma unroll
    for (int o = 1; o < 8; o <<= 1) { s += __shfl_xor(s, o); ss += __shfl_xor(ss, o); }
    const float mu = s * (1.f / 192.f);
    const float rstd = rsqrtf(ss * (1.f / 192.f) - mu * mu + 1e-5f);
    u32* dst = reinterpret_cast<u32*>(&Xn[n][c0]);
#pragma unroll
    for (int i = 0; i < 12; i++) {
      const int c = c0 + 2 * i;
      const float r0 = (v[2 * i]     - mu) * rstd * ld1(g1, c,     bf) + ld1(be1, c,     bf);
      const float r1 = (v[2 * i + 1] - mu) * rstd * ld1(g1, c + 1, bf) + ld1(be1, c + 1, bf);
      dst[i] = (u32)f2b(r0) | ((u32)f2b(r1) << 16);
    }
  }
  __syncthreads();

  const int wave = tid >> 6;
  const int lane = tid & 63;
  const int col  = lane & 15;
  const int quad = lane >> 4;
  const float scale = 0.17677669529663687f;
  const f32x4 zf = (f32x4){0.f, 0.f, 0.f, 0.f};

  for (int hp = 0; hp < 3; ++hp) {
    // ---- QKV GEMM: wave owns 48 chunk-channels (3 n-tiles) ----
    f32x4 acc[2][3];
#pragma unroll
    for (int mt = 0; mt < 2; mt++)
#pragma unroll
      for (int nt = 0; nt < 3; nt++) acc[mt][nt] = zf;

#pragma unroll
    for (int ks = 0; ks < 6; ks++) {
      short8 bfrg[3], afrg[2];
#pragma unroll
      for (int nt = 0; nt < 3; nt++)
        bfrg[nt] = gld16(wqkvT + (size_t)(hp * 192 + wave * 48 + nt * 16 + col) * 192
                                + ks * 32 + quad * 8);
#pragma unroll
      for (int mt = 0; mt < 2; mt++)
        afrg[mt] = lds16(&Xn[16 * mt + col][ks * 32 + quad * 8]);
#pragma unroll
      for (int mt = 0; mt < 2; mt++)
#pragma unroll
        for (int nt = 0; nt < 3; nt++)
          acc[mt][nt] = __builtin_amdgcn_mfma_f32_16x16x32_bf16(
              afrg[mt], bfrg[nt], acc[mt][nt], 0, 0, 0);
    }

    // ---- store Q/K ([tok][dim], pair-packed b32) and V^T ([dim][tok]) ----
#pragma unroll
    for (int nt = 0; nt < 3; nt++) {
      const int cc = wave * 48 + nt * 16 + col;       // chunk channel
      const int sel = cc >> 6, hh = (cc >> 5) & 1, d = cc & 31;
      const int j = sel * 192 + (2 * hp + hh) * 32 + d;
      const float bq = ld1(bqkv, j, bf);
      if (sel < 2) {
        u16 (*dst)[72] = (sel == 0) ? Qh : Kh;
#pragma unroll
        for (int mt = 0; mt < 2; mt++)
#pragma unroll
          for (int r = 0; r < 4; r++) {
            const u32 mine = (u32)f2b(acc[mt][nt][r] + bq);
            const u32 part = (u32)__shfl_xor((int)mine, 1);
            if (!(lane & 1))
              *(u32*)&dst[16 * mt + quad * 4 + r][hh * 32 + d] = mine | (part << 16);
          }
      } else {
#pragma unroll
        for (int mt = 0; mt < 2; mt++)
#pragma unroll
          for (int r = 0; r < 4; r++)
            VT[hh * 32 + d][16 * mt + quad * 4 + r] = f2b(acc[mt][nt][r] + bq);
      }
    }
    __syncthreads();

    // ---- attention: wave -> (head hh, query-half qh). S^T = K @ Q^T ----
    const int hh = wave >> 1, qh = wave & 1;
    const int hg = 2 * hp + hh;
    {
      const short8 bq_frag = lds16(&Qh[16 * qh + col][hh * 32 + quad * 8]);
      f32x4 sA[2];
#pragma unroll
      for (int mt = 0; mt < 2; mt++)
        sA[mt] = __builtin_amdgcn_mfma_f32_16x16x32_bf16(
            lds16(&Kh[16 * mt + col][hh * 32 + quad * 8]), bq_frag, zf, 0, 0, 0);

      const int qn = 16 * qh + col;                    // query token
      const int rn = qn >> 3, cn = qn & 7;
      const bool rhn = (whi == 15) && (rn >= 2);
      const bool rwn = (wwi == 63) && (cn >= 4);
      float sv[8];
#pragma unroll
      for (int mt = 0; mt < 2; mt++)
#pragma unroll
        for (int r = 0; r < 4; r++) {
          const int m = 16 * mt + quad * 4 + r;        // key token
          const int rm = m >> 3, cm = m & 7;
          const float bias = ld1(btab, (size_t)((rn - rm + 3) * 15 + (cn - cm + 7)) * 6 + hg, bf);
          const bool rhm = (whi == 15) && (rm >= 2);
          const bool rwm = (wwi == 63) && (cm >= 4);
          const float msk = ((rhn != rhm) || (rwn != rwm)) ? -100.f : 0.f;
          sv[4 * mt + r] = sA[mt][r] * scale + bias + msk;
        }
      float mx = sv[0];
#pragma unroll
      for (int i = 1; i < 8; i++) mx = fmaxf(mx, sv[i]);
      mx = fmaxf(mx, __shfl_xor(mx, 16));
      mx = fmaxf(mx, __shfl_xor(mx, 32));
      float sum = 0.f;
#pragma unroll
      for (int i = 0; i < 8; i++) { sv[i] = __expf(sv[i] - mx); sum += sv[i]; }
      sum += __shfl_xor(sum, 16);
      sum += __shfl_xor(sum, 32);
      const float inv = 1.f / sum;
#pragma unroll
      for (int mt = 0; mt < 2; mt++) {
        uint2 w;
        w.x = (u32)f2b(sv[4 * mt]     * inv) | ((u32)f2b(sv[4 * mt + 1] * inv) << 16);
        w.y = (u32)f2b(sv[4 * mt + 2] * inv) | ((u32)f2b(sv[4 * mt + 3] * inv) << 16);
        *reinterpret_cast<uint2*>(&Pl[hh][qn][16 * mt + quad * 4]) = w;
      }
    }
    __syncthreads();

    // ---- PV: O^T = V^T @ P^T. wave -> (head hh, dim-half qh); nt = query half
    {
      const short8 a = lds16(&VT[hh * 32 + 16 * qh + col][quad * 8]);
#pragma unroll
      for (int nt = 0; nt < 2; nt++) {
        const short8 bb = lds16(&Pl[hh][16 * nt + col][quad * 8]);
        const f32x4 o = __builtin_amdgcn_mfma_f32_16x16x32_bf16(a, bb, zf, 0, 0, 0);
        uint2 w;
        w.x = (u32)f2b(o[0]) | ((u32)f2b(o[1]) << 16);
        w.y = (u32)f2b(o[2]) | ((u32)f2b(o[3]) << 16);
        // D[row=dim=16qh+quad*4+r][col=query=16nt+col] -> Ou[query][hg*32+dim]
        *reinterpret_cast<uint2*>(&Ou[16 * nt + col][hg * 32 + 16 * qh + quad * 4]) = w;
      }
    }
    __syncthreads();
  }

  // ---- proj GEMM: M=32, N=192, K=192; + bias + residual -> out ----
  {
    f32x4 pacc[2][3];
#pragma unroll
    for (int mt = 0; mt < 2; mt++)
#pragma unroll
      for (int nt = 0; nt < 3; nt++) pacc[mt][nt] = zf;

#pragma unroll
    for (int ks = 0; ks < 6; ks++) {
      short8 bfrg[3], afrg[2];
#pragma unroll
      for (int nt = 0; nt < 3; nt++)
        bfrg[nt] = gld16(wprojT + (size_t)(wave * 48 + nt * 16 + col) * 192
                                 + ks * 32 + quad * 8);
#pragma unroll
      for (int mt = 0; mt < 2; mt++)
        afrg[mt] = lds16(&Ou[16 * mt + col][ks * 32 + quad * 8]);
#pragma unroll
      for (int mt = 0; mt < 2; mt++)
#pragma unroll
        for (int nt = 0; nt < 3; nt++)
          pacc[mt][nt] = __builtin_amdgcn_mfma_f32_16x16x32_bf16(
              afrg[mt], bfrg[nt], pacc[mt][nt], 0, 0, 0);
    }

    size_t gts[8];
#pragma unroll
    for (int mt = 0; mt < 2; mt++)
#pragma unroll
      for (int r = 0; r < 4; r++)
        gts[4 * mt + r] = (size_t)gtok(16 * mt + quad * 4 + r) * 192;

#pragma unroll
    for (int nt = 0; nt < 3; nt++) {
      const int c = wave * 48 + nt * 16 + col;
      const float bp = ld1(bproj, c, bf);
#pragma unroll
      for (int mt = 0; mt < 2; mt++)
#pragma unroll
        for (int r = 0; r < 4; r++) {
          const size_t gidx = gts[4 * mt + r] + c;
          st1(out, gidx, bf, pacc[mt][nt][r] + bp + ld1(x, gidx, bf));
        }
    }
  }
}

// ---------------------------------------------------------------------------
// Kernel B (MFMA): MLP block, in-place on d_out. 64 tokens/block, 256 thr.
// (unchanged from previous round)
// ---------------------------------------------------------------------------
__launch_bounds__(256, 2)
__global__ void swin_mlp_mfma(
    const void* __restrict__ xp,   // original x, dtype probe only
    void* __restrict__ io, const void* __restrict__ g2, const void* __restrict__ be2,
    const u16* __restrict__ w1t,   // [768][192] bf16 (transposed, in ws)
    const void* __restrict__ bm1,
    const u16* __restrict__ w2t,   // [192][768] bf16 (transposed, in ws)
    const void* __restrict__ bm2)
{
  __shared__ __align__(16) u16 Xn[64][200];   // LN2 out, [token][chan]
  __shared__ __align__(16) u16 X2[64][200];   // gelu(hidden chunk), [token][h]

  const bool bf = probe_bf16(xp);
  const int tid = threadIdx.x;
  const size_t tok0 = (size_t)blockIdx.x * 64;

  // ---- LN2 -> Xn ----
  {
    const int t = tid >> 2, g = tid & 3;
    const int c0 = 48 * g;
    const size_t base = (tok0 + t) * 192 + c0;
    float v[48];
#pragma unroll
    for (int i = 0; i < 6; i++) ld8(io, base + 8 * i, bf, v + 8 * i);
    float s = 0.f, ss = 0.f;
#pragma unroll
    for (int i = 0; i < 48; i++) { s += v[i]; ss += v[i] * v[i]; }
#pragma unroll
    for (int o = 1; o < 4; o <<= 1) { s += __shfl_xor(s, o); ss += __shfl_xor(ss, o); }
    const float mu = s * (1.f / 192.f);
    const float rstd = rsqrtf(ss * (1.f / 192.f) - mu * mu + 1e-5f);
    u32* dst = reinterpret_cast<u32*>(&Xn[t][c0]);
#pragma unroll
    for (int i = 0; i < 24; i++) {
      const int c = c0 + 2 * i;
      const float r0 = (v[2 * i]     - mu) * rstd * ld1(g2, c,     bf) + ld1(be2, c,     bf);
      const float r1 = (v[2 * i + 1] - mu) * rstd * ld1(g2, c + 1, bf) + ld1(be2, c + 1, bf);
      dst[i] = (u32)f2b(r0) | ((u32)f2b(r1) << 16);
    }
  }
  __syncthreads();

  const int wave = tid >> 6;
  const int lane = tid & 63;
  const int col  = lane & 15;     // MFMA n / C-col
  const int quad = lane >> 4;     // MFMA k-group / C-row-group

  f32x4 acc2[4][3];
#pragma unroll
  for (int mt = 0; mt < 4; mt++)
#pragma unroll
    for (int nt = 0; nt < 3; nt++) acc2[mt][nt] = (f32x4){0.f, 0.f, 0.f, 0.f};

  for (int ch = 0; ch < 4; ++ch) {
    // ---- GEMM1: hid[t][j] for j in chunk (192 wide); wave owns 48 j-cols ----
    f32x4 acc1[4][3];
#pragma unroll
    for (int mt = 0; mt < 4; mt++)
#pragma unroll
      for (int nt = 0; nt < 3; nt++) acc1[mt][nt] = (f32x4){0.f, 0.f, 0.f, 0.f};

    const int jbase = ch * 192 + wave * 48;        // global hidden col base
#pragma unroll
    for (int ks = 0; ks < 6; ks++) {
      short8 bfrg[3], afrg[4];
#pragma unroll
      for (int nt = 0; nt < 3; nt++)
        bfrg[nt] = gld16(w1t + (size_t)(jbase + nt * 16 + col) * 192 + ks * 32 + quad * 8);
#pragma unroll
      for (int mt = 0; mt < 4; mt++)
        afrg[mt] = lds16(&Xn[16 * mt + col][ks * 32 + quad * 8]);
#pragma unroll
      for (int mt = 0; mt < 4; mt++)
#pragma unroll
        for (int nt = 0; nt < 3; nt++)
          acc1[mt][nt] = __builtin_amdgcn_mfma_f32_16x16x32_bf16(
              afrg[mt], bfrg[nt], acc1[mt][nt], 0, 0, 0);
    }

    // ---- GELU + store chunk to X2 ----
#pragma unroll
    for (int nt = 0; nt < 3; nt++) {
      const float b1 = ld1(bm1, jbase + nt * 16 + col, bf);
      const int jl = wave * 48 + nt * 16 + col;    // 0..191 within chunk
#pragma unroll
      for (int mt = 0; mt < 4; mt++)
#pragma unroll
        for (int r = 0; r < 4; r++) {
          const int t = 16 * mt + quad * 4 + r;
          X2[t][jl] = f2b(gelu_t(acc1[mt][nt][r] + b1));
        }
    }
    __syncthreads();

    // ---- GEMM2 partial: acc2[t][c] += gelu_chunk @ w2_chunk ----
#pragma unroll
    for (int ks = 0; ks < 6; ks++) {
      short8 bfrg[3], afrg[4];
#pragma unroll
      for (int nt = 0; nt < 3; nt++)
        bfrg[nt] = gld16(w2t + (size_t)(wave * 48 + nt * 16 + col) * 768
                              + ch * 192 + ks * 32 + quad * 8);
#pragma unroll
      for (int mt = 0; mt < 4; mt++)
        afrg[mt] = lds16(&X2[16 * mt + col][ks * 32 + quad * 8]);
#pragma unroll
      for (int mt = 0; mt < 4; mt++)
#pragma unroll
        for (int nt = 0; nt < 3; nt++)
          acc2[mt][nt] = __builtin_amdgcn_mfma_f32_16x16x32_bf16(
              afrg[mt], bfrg[nt], acc2[mt][nt], 0, 0, 0);
    }
    __syncthreads();
  }

  // ---- epilogue: + bm2 + x1 residual, write back (per-lane RMW, race-free) ----
#pragma unroll
  for (int nt = 0; nt < 3; nt++) {
    const int c = wave * 48 + nt * 16 + col;
    const float b2 = ld1(bm2, c, bf);
#pragma unroll
    for (int mt = 0; mt < 4; mt++)
#pragma unroll
      for (int r = 0; r < 4; r++) {
        const int t = 16 * mt + quad * 4 + r;
        const size_t idx = (tok0 + t) * 192 + c;
        st1(io, idx, bf, acc2[mt][nt][r] + b2 + ld1(io, idx, bf));
      }
  }
}

extern "C" void kernel_launch(void* const* d_in, const int* in_sizes, int n_in,
                              void* d_out, int out_size, void* d_ws, size_t ws_size,
                              hipStream_t stream) {
  const void* x     = d_in[0];
  const void* g1    = d_in[3];
  const void* be1   = d_in[4];
  const void* wqkv  = d_in[5];
  const void* bqkv  = d_in[6];
  const void* wproj = d_in[7];
  const void* bproj = d_in[8];
  const void* btab  = d_in[9];
  const void* g2    = d_in[10];
  const void* be2   = d_in[11];
  const void* w1    = d_in[12];
  const void* bm1   = d_in[13];
  const void* w2    = d_in[14];
  const void* bm2   = d_in[15];

  u16* ws = (u16*)d_ws;   // w1t @0, w2t @147456, wqkvT @294912, wprojT @405504

  // 1) transpose weights into ws (442368 bf16 elems)
  transpose_weights<<<1728, 256, 0, stream>>>(w1, w2, wqkv, wproj, ws);
  // 2) attention (MFMA): one block per window, writes x1 into d_out
  swin_attn_mfma<<<8192, 256, 0, stream>>>(x, g1, be1, ws + 294912, bqkv,
                                           ws + 405504, bproj, btab, d_out);
  // 3) MLP (MFMA), in-place on d_out
  swin_mlp_mfma<<<4096, 256, 0, stream>>>(x, d_out, g2, be2, ws, bm1, ws + 147456, bm2);
}

// Round 2
// 1068.129 us; speedup vs baseline: 3.9523x; 1.2643x over previous
//
#include <hip/hip_runtime.h>
#include <hip/hip_bf16.h>

typedef unsigned short u16;
typedef unsigned int u32;
typedef __attribute__((ext_vector_type(8))) short short8;   // 8 bf16 (4 VGPRs)
typedef __attribute__((ext_vector_type(4))) float f32x4;    // MFMA acc

#define DEVFN static __device__ __forceinline__

DEVFN float b2f(u16 u) { return __uint_as_float(((u32)u) << 16); }
DEVFN void up2(u32 w, float& a, float& b) {
  a = __uint_as_float(w << 16);
  b = __uint_as_float(w & 0xffff0000u);
}
DEVFN u16 f2b(float f) {
  u32 u = __float_as_uint(f);
  return (u16)((u + 0x7fffu + ((u >> 16) & 1u)) >> 16);
}

// Detect whether buffer holds packed bf16 (vs fp32). Uniform, deterministic.
DEVFN bool probe_bf16(const void* x) {
  const u32* p = (const u32*)x;
  int cnt = 0;
  for (int i = 0; i < 64; i++) {
    u32 lo = p[i] & 0xffffu;
    u32 e = (lo >> 7) & 0xffu;
    cnt += ((lo == 0u) || (e >= 97u && e <= 132u)) ? 1 : 0;
  }
  return cnt >= 48;
}

// dtype-dual global accessors
DEVFN float ld1(const void* p, size_t i, bool bf) {
  return bf ? b2f(((const u16*)p)[i]) : ((const float*)p)[i];
}
DEVFN void st1(void* p, size_t i, bool bf, float v) {
  if (bf) ((u16*)p)[i] = f2b(v); else ((float*)p)[i] = v;
}
DEVFN void ld8(const void* p, size_t i, bool bf, float* f) {
  if (bf) {
    uint4 q = *(const uint4*)((const u16*)p + i);
    up2(q.x, f[0], f[1]); up2(q.y, f[2], f[3]);
    up2(q.z, f[4], f[5]); up2(q.w, f[6], f[7]);
  } else {
    float4 t0 = *(const float4*)((const float*)p + i);
    float4 t1 = *(const float4*)((const float*)p + i + 4);
    f[0]=t0.x; f[1]=t0.y; f[2]=t0.z; f[3]=t0.w;
    f[4]=t1.x; f[5]=t1.y; f[6]=t1.z; f[7]=t1.w;
  }
}

DEVFN short8 lds16(const u16* p) { return *reinterpret_cast<const short8*>(p); }
DEVFN short8 gld16(const u16* p) { return *reinterpret_cast<const short8*>(p); }

// LDS-only barrier: waits for DS ops but lets global (vmcnt) prefetch stay
// in flight across the barrier. All cross-wave communication in these
// kernels goes through LDS, so vmcnt(0) drain (what __syncthreads emits)
// is not required for correctness.
DEVFN void bar_lds() {
  asm volatile("s_waitcnt lgkmcnt(0)" ::: "memory");
  __builtin_amdgcn_s_barrier();
}

// tanh-approx GELU; |err| <= ~3e-3 vs exact erf-GELU
DEVFN float gelu_t(float x) {
  const float z = x * (0.7978845608f + 0.0356774081f * x * x);
  const float e = __expf(2.f * z);
  const float t = 1.f - 2.f / (e + 1.f);
  return 0.5f * x * (1.f + t);
}

// Config: B=8 H=64 W=512 C=192 NH=6 HD=32 WH=4 WW=8 SH=2 SW=4
// N=32 tokens/window, 8192 windows total. Tokens = 262144.

#define FLAG_OFF 442368

// ---------------------------------------------------------------------------
// Weight transpose into d_ws (bf16 always):
//   ws[0 .. 147455]        = w1t[768][192],   w1t[j][k]   = w1[k][j]
//   ws[147456 .. 294911]   = w2t[192][768],   w2t[c][h]   = w2[h][c]
//   ws[294912 .. 405503]   = wqkvT[576][192], row r = hp*192 + sel*64 + hh*32 + d
//   ws[405504 .. 442367]   = wprojT[192][192]
//   ws[442368]             = dtype flag (1 = bf16 inputs)
// ---------------------------------------------------------------------------
__global__ void transpose_weights(const void* __restrict__ w1,
                                  const void* __restrict__ w2,
                                  const void* __restrict__ wqkv,
                                  const void* __restrict__ wproj,
                                  u16* __restrict__ ws)
{
  const bool bf = probe_bf16(w1);
  const int idx = blockIdx.x * 256 + threadIdx.x;   // 0 .. 442367
  if (idx == 0) ws[FLAG_OFF] = bf ? 1 : 0;
  if (idx < 147456) {
    const int j = idx / 192, k = idx - 192 * j;
    ws[idx] = f2b(ld1(w1, (size_t)k * 768 + j, bf));
  } else if (idx < 294912) {
    const int i2 = idx - 147456;
    const int c = i2 / 768, h = i2 - 768 * c;
    ws[idx] = f2b(ld1(w2, (size_t)h * 192 + c, bf));
  } else if (idx < 405504) {
    const int i2 = idx - 294912;
    const int r = i2 / 192, k = i2 - 192 * r;      // r in [0,576)
    const int hp = r / 192, cc = r - 192 * hp;
    const int sel = cc >> 6, hh = (cc >> 5) & 1, d = cc & 31;
    const int j = sel * 192 + (2 * hp + hh) * 32 + d;
    ws[idx] = f2b(ld1(wqkv, (size_t)k * 576 + j, bf));
  } else {
    const int i2 = idx - 405504;
    const int n = i2 / 192, k = i2 - 192 * n;
    ws[idx] = f2b(ld1(wproj, (size_t)k * 192 + n, bf));
  }
}

// ---------------------------------------------------------------------------
// Kernel A (MFMA + register weight prefetch): one window per block, 4 waves.
// Weights for phase P+1 are loaded into wreg[18] right after phase P's MFMAs
// consume them; the store/softmax/PV phases hide the L2 latency. Barriers are
// lgkmcnt-only so prefetch survives them. All small params staged in LDS.
// ---------------------------------------------------------------------------
__launch_bounds__(256, 3)
__global__ void swin_attn_mfma(
    const void* __restrict__ x, const void* __restrict__ g1, const void* __restrict__ be1,
    const u16* __restrict__ wqkvT, const void* __restrict__ bqkv,
    const u16* __restrict__ wprojT, const void* __restrict__ bproj,
    const void* __restrict__ btab, const u16* __restrict__ bff,
    void* __restrict__ out)
{
  __shared__ __align__(16) u16 Xn[32][200];     // LN1 out [tok][cin]   12800 B
  __shared__ __align__(16) u16 Qh[32][72];      // [tok][hh*32+d]        4608 B
  __shared__ __align__(16) u16 Kh[32][72];      //                       4608 B
  __shared__ __align__(16) u16 VT[64][40];      // [hh*32+d][tok]        5120 B
  __shared__ __align__(16) u16 Pl[2][32][40];   // [hh][query][key]      5120 B
  __shared__ __align__(16) u16 Ou[32][200];     // attn out [tok][chan] 12800 B
  __shared__ u16 Pb[1792]; // btab@0[630] bqkv@640[576] bproj@1216[192] g1@1408 be1@1600

  const bool bf = bff[0] != 0;
  const int tid = threadIdx.x;
  const int wid = blockIdx.x;
  const int b   = wid >> 10;
  const int wli = wid & 1023;
  const int whi = wli >> 6;
  const int wwi = wli & 63;

  auto gtok = [&](int n) -> int {
    const int r = n >> 3, c = n & 7;
    const int ho = (whi * 4 + r + 2) & 63;
    const int wo = (wwi * 8 + c + 4) & 511;
    return (b << 15) + ho * 512 + wo;
  };

  const int wave = tid >> 6;
  const int lane = tid & 63;
  const int col  = lane & 15;
  const int quad = lane >> 4;

  // ---- stage small params into LDS (consumed loads, before prefetch) ----
#pragma unroll
  for (int i0 = 0; i0 < 7; i0++) {
    const int i = i0 * 256 + tid;
    float v = 0.f;
    if (i < 630) v = ld1(btab, i, bf);
    else if (i >= 1600) v = ld1(be1, i - 1600, bf);
    else if (i >= 1408) v = ld1(g1, i - 1408, bf);
    else if (i >= 1216) v = ld1(bproj, i - 1216, bf);
    else if (i >= 640) v = ld1(bqkv, i - 640, bf);
    Pb[i] = f2b(v);
  }

  // ---- LN1 input loads, then hp=0 weight prefetch (hides under LN) ----
  short8 wreg[18];
  float v[24];
  const int ln_n = tid >> 3, ln_g = tid & 7, ln_c0 = ln_g * 24;
  {
    const size_t base = (size_t)gtok(ln_n) * 192 + ln_c0;
    ld8(x, base, bf, v); ld8(x, base + 8, bf, v + 8); ld8(x, base + 16, bf, v + 16);
  }
  {
    const u16* wb = wqkvT + (size_t)(wave * 48 + col) * 192 + quad * 8;
#pragma unroll
    for (int nt = 0; nt < 3; nt++)
#pragma unroll
      for (int ks = 0; ks < 6; ks++)
        wreg[nt * 6 + ks] = gld16(wb + nt * 16 * 192 + ks * 32);
  }
  bar_lds();   // Pb visible

  // ---- LN1 compute -> Xn ----
  {
    float s = 0.f, ss = 0.f;
#pragma unroll
    for (int i = 0; i < 24; i++) { s += v[i]; ss += v[i] * v[i]; }
#pragma unroll
    for (int o = 1; o < 8; o <<= 1) { s += __shfl_xor(s, o); ss += __shfl_xor(ss, o); }
    const float mu = s * (1.f / 192.f);
    const float rstd = rsqrtf(ss * (1.f / 192.f) - mu * mu + 1e-5f);
    u32* dst = reinterpret_cast<u32*>(&Xn[ln_n][ln_c0]);
#pragma unroll
    for (int i = 0; i < 12; i++) {
      const int c = ln_c0 + 2 * i;
      const float r0 = (v[2*i]   - mu) * rstd * b2f(Pb[1408 + c])     + b2f(Pb[1600 + c]);
      const float r1 = (v[2*i+1] - mu) * rstd * b2f(Pb[1408 + c + 1]) + b2f(Pb[1600 + c + 1]);
      dst[i] = (u32)f2b(r0) | ((u32)f2b(r1) << 16);
    }
  }
  bar_lds();   // Xn visible

  const float scale = 0.17677669529663687f;
  const f32x4 zf = (f32x4){0.f, 0.f, 0.f, 0.f};
  const int hh = wave >> 1, qh = wave & 1;

  for (int hp = 0; hp < 3; ++hp) {
    // ---- QKV GEMM: consume wreg (already resident) ----
    f32x4 acc[2][3];
#pragma unroll
    for (int mt = 0; mt < 2; mt++)
#pragma unroll
      for (int nt = 0; nt < 3; nt++) acc[mt][nt] = zf;

#pragma unroll
    for (int ks = 0; ks < 6; ks++) {
      short8 afrg[2];
#pragma unroll
      for (int mt = 0; mt < 2; mt++)
        afrg[mt] = lds16(&Xn[16 * mt + col][ks * 32 + quad * 8]);
#pragma unroll
      for (int mt = 0; mt < 2; mt++)
#pragma unroll
        for (int nt = 0; nt < 3; nt++)
          acc[mt][nt] = __builtin_amdgcn_mfma_f32_16x16x32_bf16(
              afrg[mt], wreg[nt * 6 + ks], acc[mt][nt], 0, 0, 0);
    }

    // ---- prefetch next phase's weights (hp+1 QKV, or proj) ----
    {
      const u16* wb = (hp < 2)
        ? wqkvT + (size_t)((hp + 1) * 192 + wave * 48 + col) * 192 + quad * 8
        : wprojT + (size_t)(wave * 48 + col) * 192 + quad * 8;
#pragma unroll
      for (int nt = 0; nt < 3; nt++)
#pragma unroll
        for (int ks = 0; ks < 6; ks++)
          wreg[nt * 6 + ks] = gld16(wb + nt * 16 * 192 + ks * 32);
    }

    // ---- store Q/K ([tok][dim], pair-packed b32) and V^T ([dim][tok]) ----
#pragma unroll
    for (int nt = 0; nt < 3; nt++) {
      const int cc = wave * 48 + nt * 16 + col;       // chunk channel
      const int sel = cc >> 6, hhs = (cc >> 5) & 1, d = cc & 31;
      const int j = sel * 192 + (2 * hp + hhs) * 32 + d;
      const float bq = b2f(Pb[640 + j]);
      if (sel < 2) {
        u16 (*dst)[72] = (sel == 0) ? Qh : Kh;
#pragma unroll
        for (int mt = 0; mt < 2; mt++)
#pragma unroll
          for (int r = 0; r < 4; r++) {
            const u32 mine = (u32)f2b(acc[mt][nt][r] + bq);
            const u32 part = (u32)__shfl_xor((int)mine, 1);
            if (!(lane & 1))
              *(u32*)&dst[16 * mt + quad * 4 + r][hhs * 32 + d] = mine | (part << 16);
          }
      } else {
#pragma unroll
        for (int mt = 0; mt < 2; mt++)
#pragma unroll
          for (int r = 0; r < 4; r++)
            VT[hhs * 32 + d][16 * mt + quad * 4 + r] = f2b(acc[mt][nt][r] + bq);
      }
    }
    bar_lds();

    // ---- attention: wave -> (head hh, query-half qh). S^T = K @ Q^T ----
    const int hg = 2 * hp + hh;
    {
      const short8 bq_frag = lds16(&Qh[16 * qh + col][hh * 32 + quad * 8]);
      f32x4 sA[2];
#pragma unroll
      for (int mt = 0; mt < 2; mt++)
        sA[mt] = __builtin_amdgcn_mfma_f32_16x16x32_bf16(
            lds16(&Kh[16 * mt + col][hh * 32 + quad * 8]), bq_frag, zf, 0, 0, 0);

      const int qn = 16 * qh + col;                    // query token
      const int rn = qn >> 3, cn = qn & 7;
      const bool rhn = (whi == 15) && (rn >= 2);
      const bool rwn = (wwi == 63) && (cn >= 4);
      float sv[8];
#pragma unroll
      for (int mt = 0; mt < 2; mt++)
#pragma unroll
        for (int r = 0; r < 4; r++) {
          const int m = 16 * mt + quad * 4 + r;        // key token
          const int rm = m >> 3, cm = m & 7;
          const float bias = b2f(Pb[((rn - rm + 3) * 15 + (cn - cm + 7)) * 6 + hg]);
          const bool rhm = (whi == 15) && (rm >= 2);
          const bool rwm = (wwi == 63) && (cm >= 4);
          const float msk = ((rhn != rhm) || (rwn != rwm)) ? -100.f : 0.f;
          sv[4 * mt + r] = sA[mt][r] * scale + bias + msk;
        }
      float mx = sv[0];
#pragma unroll
      for (int i = 1; i < 8; i++) mx = fmaxf(mx, sv[i]);
      mx = fmaxf(mx, __shfl_xor(mx, 16));
      mx = fmaxf(mx, __shfl_xor(mx, 32));
      float sum = 0.f;
#pragma unroll
      for (int i = 0; i < 8; i++) { sv[i] = __expf(sv[i] - mx); sum += sv[i]; }
      sum += __shfl_xor(sum, 16);
      sum += __shfl_xor(sum, 32);
      const float inv = 1.f / sum;
#pragma unroll
      for (int mt = 0; mt < 2; mt++) {
        uint2 w;
        w.x = (u32)f2b(sv[4 * mt]     * inv) | ((u32)f2b(sv[4 * mt + 1] * inv) << 16);
        w.y = (u32)f2b(sv[4 * mt + 2] * inv) | ((u32)f2b(sv[4 * mt + 3] * inv) << 16);
        *reinterpret_cast<uint2*>(&Pl[hh][qn][16 * mt + quad * 4]) = w;
      }
    }
    bar_lds();

    // ---- PV: O^T = V^T @ P^T. wave -> (head hh, dim-half qh) ----
    {
      const short8 a = lds16(&VT[hh * 32 + 16 * qh + col][quad * 8]);
#pragma unroll
      for (int nt = 0; nt < 2; nt++) {
        const short8 bb = lds16(&Pl[hh][16 * nt + col][quad * 8]);
        const f32x4 o = __builtin_amdgcn_mfma_f32_16x16x32_bf16(a, bb, zf, 0, 0, 0);
        uint2 w;
        w.x = (u32)f2b(o[0]) | ((u32)f2b(o[1]) << 16);
        w.y = (u32)f2b(o[2]) | ((u32)f2b(o[3]) << 16);
        *reinterpret_cast<uint2*>(&Ou[16 * nt + col][hg * 32 + 16 * qh + quad * 4]) = w;
      }
    }
    bar_lds();
  }

  // ---- proj GEMM (wreg holds wprojT frags): + bias + residual -> out ----
  {
    f32x4 pacc[2][3];
#pragma unroll
    for (int mt = 0; mt < 2; mt++)
#pragma unroll
      for (int nt = 0; nt < 3; nt++) pacc[mt][nt] = zf;

#pragma unroll
    for (int ks = 0; ks < 6; ks++) {
      short8 afrg[2];
#pragma unroll
      for (int mt = 0; mt < 2; mt++)
        afrg[mt] = lds16(&Ou[16 * mt + col][ks * 32 + quad * 8]);
#pragma unroll
      for (int mt = 0; mt < 2; mt++)
#pragma unroll
        for (int nt = 0; nt < 3; nt++)
          pacc[mt][nt] = __builtin_amdgcn_mfma_f32_16x16x32_bf16(
              afrg[mt], wreg[nt * 6 + ks], pacc[mt][nt], 0, 0, 0);
    }

    size_t gts[8];
#pragma unroll
    for (int mt = 0; mt < 2; mt++)
#pragma unroll
      for (int r = 0; r < 4; r++)
        gts[4 * mt + r] = (size_t)gtok(16 * mt + quad * 4 + r) * 192;

#pragma unroll
    for (int nt = 0; nt < 3; nt++) {
      const int c = wave * 48 + nt * 16 + col;
      const float bp = b2f(Pb[1216 + c]);
#pragma unroll
      for (int mt = 0; mt < 2; mt++)
#pragma unroll
        for (int r = 0; r < 4; r++) {
          const size_t gidx = gts[4 * mt + r] + c;
          st1(out, gidx, bf, pacc[mt][nt][r] + bp + ld1(x, gidx, bf));
        }
    }
  }
}

// ---------------------------------------------------------------------------
// Kernel B (MFMA + prefetch): MLP, in-place on d_out. 64 tokens/block.
// Hidden (768) in 6 chunks of 128 -> LDS 44.9 KB -> 3 blocks/CU.
// wreg[12] ping-pongs between W1 (2x6) and W2 (3x4) fragment sets.
// ---------------------------------------------------------------------------
__launch_bounds__(256, 3)
__global__ void swin_mlp_mfma(
    const u16* __restrict__ bff,
    void* __restrict__ io, const void* __restrict__ g2, const void* __restrict__ be2,
    const u16* __restrict__ w1t,   // [768][192] bf16
    const void* __restrict__ bm1,
    const u16* __restrict__ w2t,   // [192][768] bf16
    const void* __restrict__ bm2)
{
  __shared__ __align__(16) u16 Xn[64][200];   // LN2 out [tok][chan]  25600 B
  __shared__ __align__(16) u16 X2[64][136];   // gelu chunk [tok][j]  17408 B
  __shared__ u16 Pm[1344];  // bm1@0[768] bm2@768[192] g2@960[192] be2@1152[192]

  const bool bf = bff[0] != 0;
  const int tid = threadIdx.x;
  const size_t tok0 = (size_t)blockIdx.x * 64;
  const int wave = tid >> 6;
  const int lane = tid & 63;
  const int col  = lane & 15;
  const int quad = lane >> 4;

  // ---- stage params ----
#pragma unroll
  for (int i0 = 0; i0 < 6; i0++) {
    const int i = i0 * 256 + tid;
    if (i < 1344) {
      float vv;
      if (i < 768) vv = ld1(bm1, i, bf);
      else if (i < 960) vv = ld1(bm2, i - 768, bf);
      else if (i < 1152) vv = ld1(g2, i - 960, bf);
      else vv = ld1(be2, i - 1152, bf);
      Pm[i] = f2b(vv);
    }
  }

  // ---- LN2 loads, then W1(ch0) prefetch ----
  short8 wreg[12];
  float v[48];
  const int ln_t = tid >> 2, ln_g = tid & 3, ln_c0 = 48 * ln_g;
  {
    const size_t base = (tok0 + ln_t) * 192 + ln_c0;
#pragma unroll
    for (int i = 0; i < 6; i++) ld8(io, base + 8 * i, bf, v + 8 * i);
  }
  {
    const u16* wb = w1t + (size_t)(wave * 32 + col) * 192 + quad * 8;
#pragma unroll
    for (int nt = 0; nt < 2; nt++)
#pragma unroll
      for (int ks = 0; ks < 6; ks++)
        wreg[nt * 6 + ks] = gld16(wb + nt * 16 * 192 + ks * 32);
  }
  bar_lds();   // Pm visible

  // ---- LN2 compute -> Xn ----
  {
    float s = 0.f, ss = 0.f;
#pragma unroll
    for (int i = 0; i < 48; i++) { s += v[i]; ss += v[i] * v[i]; }
#pragma unroll
    for (int o = 1; o < 4; o <<= 1) { s += __shfl_xor(s, o); ss += __shfl_xor(ss, o); }
    const float mu = s * (1.f / 192.f);
    const float rstd = rsqrtf(ss * (1.f / 192.f) - mu * mu + 1e-5f);
    u32* dst = reinterpret_cast<u32*>(&Xn[ln_t][ln_c0]);
#pragma unroll
    for (int i = 0; i < 24; i++) {
      const int c = ln_c0 + 2 * i;
      const float r0 = (v[2*i]   - mu) * rstd * b2f(Pm[960 + c])     + b2f(Pm[1152 + c]);
      const float r1 = (v[2*i+1] - mu) * rstd * b2f(Pm[960 + c + 1]) + b2f(Pm[1152 + c + 1]);
      dst[i] = (u32)f2b(r0) | ((u32)f2b(r1) << 16);
    }
  }
  bar_lds();   // Xn visible

  f32x4 acc2[4][3];
#pragma unroll
  for (int mt = 0; mt < 4; mt++)
#pragma unroll
    for (int nt = 0; nt < 3; nt++) acc2[mt][nt] = (f32x4){0.f, 0.f, 0.f, 0.f};

  for (int ch = 0; ch < 6; ++ch) {
    // ---- GEMM1: 128-wide hidden chunk; wave owns 32 j-cols ----
    f32x4 acc1[4][2];
#pragma unroll
    for (int mt = 0; mt < 4; mt++)
#pragma unroll
      for (int nt = 0; nt < 2; nt++) acc1[mt][nt] = (f32x4){0.f, 0.f, 0.f, 0.f};

#pragma unroll
    for (int ks = 0; ks < 6; ks++) {
      short8 afrg[4];
#pragma unroll
      for (int mt = 0; mt < 4; mt++)
        afrg[mt] = lds16(&Xn[16 * mt + col][ks * 32 + quad * 8]);
#pragma unroll
      for (int mt = 0; mt < 4; mt++)
#pragma unroll
        for (int nt = 0; nt < 2; nt++)
          acc1[mt][nt] = __builtin_amdgcn_mfma_f32_16x16x32_bf16(
              afrg[mt], wreg[nt * 6 + ks], acc1[mt][nt], 0, 0, 0);
    }

    // ---- prefetch W2(ch) fragments (hide under GELU) ----
    {
      const u16* wb = w2t + (size_t)(wave * 48 + col) * 768 + ch * 128 + quad * 8;
#pragma unroll
      for (int nt = 0; nt < 3; nt++)
#pragma unroll
        for (int ks = 0; ks < 4; ks++)
          wreg[nt * 4 + ks] = gld16(wb + nt * 16 * 768 + ks * 32);
    }

    // ---- GELU + store chunk to X2 ----
    const int jbase = ch * 128 + wave * 32;
#pragma unroll
    for (int nt = 0; nt < 2; nt++) {
      const float b1 = b2f(Pm[jbase + nt * 16 + col]);
      const int jl = wave * 32 + nt * 16 + col;    // 0..127 within chunk
#pragma unroll
      for (int mt = 0; mt < 4; mt++)
#pragma unroll
        for (int r = 0; r < 4; r++) {
          const int t = 16 * mt + quad * 4 + r;
          X2[t][jl] = f2b(gelu_t(acc1[mt][nt][r] + b1));
        }
    }
    bar_lds();

    // ---- GEMM2 partial: acc2 += gelu_chunk @ w2_chunk ----
#pragma unroll
    for (int ks = 0; ks < 4; ks++) {
      short8 afrg[4];
#pragma unroll
      for (int mt = 0; mt < 4; mt++)
        afrg[mt] = lds16(&X2[16 * mt + col][ks * 32 + quad * 8]);
#pragma unroll
      for (int mt = 0; mt < 4; mt++)
#pragma unroll
        for (int nt = 0; nt < 3; nt++)
          acc2[mt][nt] = __builtin_amdgcn_mfma_f32_16x16x32_bf16(
              afrg[mt], wreg[nt * 4 + ks], acc2[mt][nt], 0, 0, 0);
    }

    // ---- prefetch W1(ch+1) fragments ----
    if (ch < 5) {
      const u16* wb = w1t + (size_t)((ch + 1) * 128 + wave * 32 + col) * 192 + quad * 8;
#pragma unroll
      for (int nt = 0; nt < 2; nt++)
#pragma unroll
        for (int ks = 0; ks < 6; ks++)
          wreg[nt * 6 + ks] = gld16(wb + nt * 16 * 192 + ks * 32);
    }
    bar_lds();
  }

  // ---- epilogue: + bm2 + x1 residual, write back (per-lane RMW) ----
#pragma unroll
  for (int nt = 0; nt < 3; nt++) {
    const int c = wave * 48 + nt * 16 + col;
    const float b2 = b2f(Pm[768 + c]);
#pragma unroll
    for (int mt = 0; mt < 4; mt++)
#pragma unroll
      for (int r = 0; r < 4; r++) {
        const int t = 16 * mt + quad * 4 + r;
        const size_t idx = (tok0 + t) * 192 + c;
        st1(io, idx, bf, acc2[mt][nt][r] + b2 + ld1(io, idx, bf));
      }
  }
}

extern "C" void kernel_launch(void* const* d_in, const int* in_sizes, int n_in,
                              void* d_out, int out_size, void* d_ws, size_t ws_size,
                              hipStream_t stream) {
  const void* x     = d_in[0];
  const void* g1    = d_in[3];
  const void* be1   = d_in[4];
  const void* wqkv  = d_in[5];
  const void* bqkv  = d_in[6];
  const void* wproj = d_in[7];
  const void* bproj = d_in[8];
  const void* btab  = d_in[9];
  const void* g2    = d_in[10];
  const void* be2   = d_in[11];
  const void* w1    = d_in[12];
  const void* bm1   = d_in[13];
  const void* w2    = d_in[14];
  const void* bm2   = d_in[15];

  u16* ws = (u16*)d_ws;   // w1t @0, w2t @147456, wqkvT @294912, wprojT @405504, flag @442368

  // 1) transpose weights into ws + dtype flag
  transpose_weights<<<1728, 256, 0, stream>>>(w1, w2, wqkv, wproj, ws);
  // 2) attention (MFMA): one block per window, writes x1 into d_out
  swin_attn_mfma<<<8192, 256, 0, stream>>>(x, g1, be1, ws + 294912, bqkv,
                                           ws + 405504, bproj, btab,
                                           ws + FLAG_OFF, d_out);
  // 3) MLP (MFMA), in-place on d_out
  swin_mlp_mfma<<<4096, 256, 0, stream>>>(ws + FLAG_OFF, d_out, g2, be2,
                                          ws, bm1, ws + 147456, bm2);
}

// Round 4
// 977.223 us; speedup vs baseline: 4.3199x; 1.0930x over previous
//
#include <hip/hip_runtime.h>
#include <hip/hip_bf16.h>

typedef unsigned short u16;
typedef unsigned int u32;
typedef __attribute__((ext_vector_type(8))) short short8;   // 8 bf16 (4 VGPRs)
typedef __attribute__((ext_vector_type(4))) float f32x4;    // MFMA acc

#define DEVFN static __device__ __forceinline__

DEVFN float b2f(u16 u) { return __uint_as_float(((u32)u) << 16); }
DEVFN void up2(u32 w, float& a, float& b) {
  a = __uint_as_float(w << 16);
  b = __uint_as_float(w & 0xffff0000u);
}
DEVFN u16 f2b(float f) {
  u32 u = __float_as_uint(f);
  return (u16)((u + 0x7fffu + ((u >> 16) & 1u)) >> 16);
}
DEVFN u32 pk2(float a, float b) {
  return (u32)f2b(a) | ((u32)f2b(b) << 16);
}

// Detect whether buffer holds packed bf16 (vs fp32). Uniform, deterministic.
DEVFN bool probe_bf16(const void* x) {
  const u32* p = (const u32*)x;
  int cnt = 0;
  for (int i = 0; i < 64; i++) {
    u32 lo = p[i] & 0xffffu;
    u32 e = (lo >> 7) & 0xffu;
    cnt += ((lo == 0u) || (e >= 97u && e <= 132u)) ? 1 : 0;
  }
  return cnt >= 48;
}

// dtype-dual global accessors
DEVFN float ld1(const void* p, size_t i, bool bf) {
  return bf ? b2f(((const u16*)p)[i]) : ((const float*)p)[i];
}
DEVFN void ld8(const void* p, size_t i, bool bf, float* f) {
  if (bf) {
    uint4 q = *(const uint4*)((const u16*)p + i);
    up2(q.x, f[0], f[1]); up2(q.y, f[2], f[3]);
    up2(q.z, f[4], f[5]); up2(q.w, f[6], f[7]);
  } else {
    float4 t0 = *(const float4*)((const float*)p + i);
    float4 t1 = *(const float4*)((const float*)p + i + 4);
    f[0]=t0.x; f[1]=t0.y; f[2]=t0.z; f[3]=t0.w;
    f[4]=t1.x; f[5]=t1.y; f[6]=t1.z; f[7]=t1.w;
  }
}
DEVFN void ld4f(const void* p, size_t i, bool bf, float* f) {
  if (bf) {
    uint2 q = *(const uint2*)((const u16*)p + i);
    up2(q.x, f[0], f[1]); up2(q.y, f[2], f[3]);
  } else {
    float4 t = *(const float4*)((const float*)p + i);
    f[0]=t.x; f[1]=t.y; f[2]=t.z; f[3]=t.w;
  }
}
DEVFN void st4f(void* p, size_t i, bool bf, const float* f) {
  if (bf) {
    uint2 q; q.x = pk2(f[0], f[1]); q.y = pk2(f[2], f[3]);
    *(uint2*)((u16*)p + i) = q;
  } else {
    float4 t; t.x=f[0]; t.y=f[1]; t.z=f[2]; t.w=f[3];
    *(float4*)((float*)p + i) = t;
  }
}

DEVFN short8 lds16(const u16* p) { return *reinterpret_cast<const short8*>(p); }
DEVFN short8 gld16(const u16* p) { return *reinterpret_cast<const short8*>(p); }

// LDS-only barrier: waits for DS ops but lets global (vmcnt) prefetch stay
// in flight across the barrier. sched_barrier(0) fences pin the s_barrier so
// no LDS read/write can be scheduled across it (rule #18 / m152 race class).
DEVFN void bar_lds() {
  __builtin_amdgcn_sched_barrier(0);
  asm volatile("s_waitcnt lgkmcnt(0)" ::: "memory");
  __builtin_amdgcn_s_barrier();
  __builtin_amdgcn_sched_barrier(0);
}

// tanh-approx GELU; |err| <= ~3e-3 vs exact erf-GELU
DEVFN float gelu_t(float x) {
  const float z = x * (0.7978845608f + 0.0356774081f * x * x);
  const float e = __expf(2.f * z);
  const float t = 1.f - 2.f / (e + 1.f);
  return 0.5f * x * (1.f + t);
}

// Config: B=8 H=64 W=512 C=192 NH=6 HD=32 WH=4 WW=8 SH=2 SW=4
// N=32 tokens/window, 8192 windows total. Tokens = 262144.

#define FLAG_OFF 442368

// ---------------------------------------------------------------------------
// Weight transpose into d_ws (bf16 always):
//   ws[0 .. 147455]        = w1t[768][192],   w1t[j][k]   = w1[k][j]
//   ws[147456 .. 294911]   = w2t[192][768],   w2t[c][h]   = w2[h][c]
//   ws[294912 .. 405503]   = wqkvT[576][192], row r = hp*192 + sel*64 + hh*32 + d
//   ws[405504 .. 442367]   = wprojT[192][192]
//   ws[442368]             = dtype flag (1 = bf16 inputs)
// ---------------------------------------------------------------------------
__global__ void transpose_weights(const void* __restrict__ w1,
                                  const void* __restrict__ w2,
                                  const void* __restrict__ wqkv,
                                  const void* __restrict__ wproj,
                                  u16* __restrict__ ws)
{
  const bool bf = probe_bf16(w1);
  const int idx = blockIdx.x * 256 + threadIdx.x;   // 0 .. 442367
  if (idx == 0) ws[FLAG_OFF] = bf ? 1 : 0;
  if (idx < 147456) {
    const int j = idx / 192, k = idx - 192 * j;
    ws[idx] = f2b(ld1(w1, (size_t)k * 768 + j, bf));
  } else if (idx < 294912) {
    const int i2 = idx - 147456;
    const int c = i2 / 768, h = i2 - 768 * c;
    ws[idx] = f2b(ld1(w2, (size_t)h * 192 + c, bf));
  } else if (idx < 405504) {
    const int i2 = idx - 294912;
    const int r = i2 / 192, k = i2 - 192 * r;      // r in [0,576)
    const int hp = r / 192, cc = r - 192 * hp;
    const int sel = cc >> 6, hh = (cc >> 5) & 1, d = cc & 31;
    const int j = sel * 192 + (2 * hp + hh) * 32 + d;
    ws[idx] = f2b(ld1(wqkv, (size_t)k * 576 + j, bf));
  } else {
    const int i2 = idx - 405504;
    const int n = i2 / 192, k = i2 - 192 * n;
    ws[idx] = f2b(ld1(wproj, (size_t)k * 192 + n, bf));
  }
}

// ---------------------------------------------------------------------------
// Kernel A: one window per block, 4 waves. GEMMs computed TRANSPOSED
// (weights as A operand -> D rows = out-channel, 4 contiguous per lane) so
// Q/K stores and the proj epilogue are packed uint2/float4 ops. Weight frags
// for phase P+1 prefetched into wreg[18] while phase P's softmax/PV runs;
// barriers are lgkmcnt-only (hardened) so prefetch survives them.
// ---------------------------------------------------------------------------
__launch_bounds__(256, 3)
__global__ void swin_attn_mfma(
    const void* __restrict__ x, const void* __restrict__ g1, const void* __restrict__ be1,
    const u16* __restrict__ wqkvT, const void* __restrict__ bqkv,
    const u16* __restrict__ wprojT, const void* __restrict__ bproj,
    const void* __restrict__ btab, const u16* __restrict__ bff,
    void* __restrict__ out)
{
  __shared__ __align__(16) u16 Xn[32][200];     // LN1 out [tok][cin]   12800 B
  __shared__ __align__(16) u16 Qh[32][72];      // [tok][hh*32+d]        4608 B
  __shared__ __align__(16) u16 Kh[32][72];      //                       4608 B
  __shared__ __align__(16) u16 VT[64][40];      // [hh*32+d][tok]        5120 B
  __shared__ __align__(16) u16 Pl[2][32][40];   // [hh][query][key]      5120 B
  __shared__ __align__(16) u16 Ou[32][200];     // attn out [tok][chan] 12800 B
  __shared__ u16 Pb[1792]; // btab@0[630] bqkv@640[576] bproj@1216[192] g1@1408 be1@1600

  const bool bf = bff[0] != 0;
  const int tid = threadIdx.x;
  const int wid = blockIdx.x;
  const int b   = wid >> 10;
  const int wli = wid & 1023;
  const int whi = wli >> 6;
  const int wwi = wli & 63;

  auto gtok = [&](int n) -> int {
    const int r = n >> 3, c = n & 7;
    const int ho = (whi * 4 + r + 2) & 63;
    const int wo = (wwi * 8 + c + 4) & 511;
    return (b << 15) + ho * 512 + wo;
  };

  const int wave = tid >> 6;
  const int lane = tid & 63;
  const int col  = lane & 15;
  const int quad = lane >> 4;

  // ---- stage small params into LDS (consumed loads, before prefetch) ----
#pragma unroll
  for (int i0 = 0; i0 < 7; i0++) {
    const int i = i0 * 256 + tid;
    float v = 0.f;
    if (i < 630) v = ld1(btab, i, bf);
    else if (i >= 1600) v = ld1(be1, i - 1600, bf);
    else if (i >= 1408) v = ld1(g1, i - 1408, bf);
    else if (i >= 1216) v = ld1(bproj, i - 1216, bf);
    else if (i >= 640) v = ld1(bqkv, i - 640, bf);
    Pb[i] = f2b(v);
  }

  // ---- LN1 input loads, then hp=0 weight prefetch (hides under LN) ----
  short8 wreg[18];
  float v[24];
  const int ln_n = tid >> 3, ln_g = tid & 7, ln_c0 = ln_g * 24;
  {
    const size_t base = (size_t)gtok(ln_n) * 192 + ln_c0;
    ld8(x, base, bf, v); ld8(x, base + 8, bf, v + 8); ld8(x, base + 16, bf, v + 16);
  }
  {
    const u16* wb = wqkvT + (size_t)(wave * 48 + col) * 192 + quad * 8;
#pragma unroll
    for (int mt = 0; mt < 3; mt++)
#pragma unroll
      for (int ks = 0; ks < 6; ks++)
        wreg[mt * 6 + ks] = gld16(wb + mt * 16 * 192 + ks * 32);
  }
  bar_lds();   // Pb visible

  // ---- LN1 compute -> Xn ----
  {
    float s = 0.f, ss = 0.f;
#pragma unroll
    for (int i = 0; i < 24; i++) { s += v[i]; ss += v[i] * v[i]; }
#pragma unroll
    for (int o = 1; o < 8; o <<= 1) { s += __shfl_xor(s, o); ss += __shfl_xor(ss, o); }
    const float mu = s * (1.f / 192.f);
    const float rstd = rsqrtf(ss * (1.f / 192.f) - mu * mu + 1e-5f);
    u32* dst = reinterpret_cast<u32*>(&Xn[ln_n][ln_c0]);
#pragma unroll
    for (int i = 0; i < 12; i++) {
      const int c = ln_c0 + 2 * i;
      const float r0 = (v[2*i]   - mu) * rstd * b2f(Pb[1408 + c])     + b2f(Pb[1600 + c]);
      const float r1 = (v[2*i+1] - mu) * rstd * b2f(Pb[1408 + c + 1]) + b2f(Pb[1600 + c + 1]);
      dst[i] = pk2(r0, r1);
    }
  }
  bar_lds();   // Xn visible

  const float scale = 0.17677669529663687f;
  const f32x4 zf = (f32x4){0.f, 0.f, 0.f, 0.f};
  const int hh = wave >> 1, qh = wave & 1;

  for (int hp = 0; hp < 3; ++hp) {
    // ---- QKV GEMM (transposed): D[chan][tok]; wave owns 48 chans ----
    f32x4 acc[3][2];
#pragma unroll
    for (int mt = 0; mt < 3; mt++)
#pragma unroll
      for (int nt = 0; nt < 2; nt++) acc[mt][nt] = zf;

#pragma unroll
    for (int ks = 0; ks < 6; ks++) {
      short8 xf[2];
#pragma unroll
      for (int nt = 0; nt < 2; nt++)
        xf[nt] = lds16(&Xn[16 * nt + col][ks * 32 + quad * 8]);
#pragma unroll
      for (int mt = 0; mt < 3; mt++)
#pragma unroll
        for (int nt = 0; nt < 2; nt++)
          acc[mt][nt] = __builtin_amdgcn_mfma_f32_16x16x32_bf16(
              wreg[mt * 6 + ks], xf[nt], acc[mt][nt], 0, 0, 0);
    }

    // ---- prefetch next phase's weights (hp+1 QKV, or proj) ----
    {
      const u16* wb = (hp < 2)
        ? wqkvT + (size_t)((hp + 1) * 192 + wave * 48 + col) * 192 + quad * 8
        : wprojT + (size_t)(wave * 48 + col) * 192 + quad * 8;
#pragma unroll
      for (int mt = 0; mt < 3; mt++)
#pragma unroll
        for (int ks = 0; ks < 6; ks++)
          wreg[mt * 6 + ks] = gld16(wb + mt * 16 * 192 + ks * 32);
    }

    // ---- store Q/K ([tok][dim], packed uint2) and V^T ([dim][tok]) ----
#pragma unroll
    for (int mt = 0; mt < 3; mt++) {
      const int cc0 = wave * 48 + 16 * mt + quad * 4;   // 4 contiguous chans
      const int sel = cc0 >> 6, hhs = (cc0 >> 5) & 1, d0 = cc0 & 31;
      const int jb = sel * 192 + (2 * hp + hhs) * 32 + d0;
      float bq[4];
#pragma unroll
      for (int r = 0; r < 4; r++) bq[r] = b2f(Pb[640 + jb + r]);
      if (sel < 2) {
        u16 (*dst)[72] = (sel == 0) ? Qh : Kh;
#pragma unroll
        for (int nt = 0; nt < 2; nt++) {
          const int tok = 16 * nt + col;
          uint2 w;
          w.x = pk2(acc[mt][nt][0] + bq[0], acc[mt][nt][1] + bq[1]);
          w.y = pk2(acc[mt][nt][2] + bq[2], acc[mt][nt][3] + bq[3]);
          *reinterpret_cast<uint2*>(&dst[tok][hhs * 32 + d0]) = w;
        }
      } else {
#pragma unroll
        for (int nt = 0; nt < 2; nt++) {
          const int tok = 16 * nt + col;
#pragma unroll
          for (int r = 0; r < 4; r++)
            VT[hhs * 32 + d0 + r][tok] = f2b(acc[mt][nt][r] + bq[r]);
        }
      }
    }
    bar_lds();

    // ---- attention: wave -> (head hh, query-half qh). S^T = K @ Q^T ----
    const int hg = 2 * hp + hh;
    {
      const short8 bq_frag = lds16(&Qh[16 * qh + col][hh * 32 + quad * 8]);
      f32x4 sA[2];
#pragma unroll
      for (int mt = 0; mt < 2; mt++)
        sA[mt] = __builtin_amdgcn_mfma_f32_16x16x32_bf16(
            lds16(&Kh[16 * mt + col][hh * 32 + quad * 8]), bq_frag, zf, 0, 0, 0);

      const int qn = 16 * qh + col;                    // query token
      const int rn = qn >> 3, cn = qn & 7;
      const bool rhn = (whi == 15) && (rn >= 2);
      const bool rwn = (wwi == 63) && (cn >= 4);
      float sv[8];
#pragma unroll
      for (int mt = 0; mt < 2; mt++)
#pragma unroll
        for (int r = 0; r < 4; r++) {
          const int m = 16 * mt + quad * 4 + r;        // key token
          const int rm = m >> 3, cm = m & 7;
          const float bias = b2f(Pb[((rn - rm + 3) * 15 + (cn - cm + 7)) * 6 + hg]);
          const bool rhm = (whi == 15) && (rm >= 2);
          const bool rwm = (wwi == 63) && (cm >= 4);
          const float msk = ((rhn != rhm) || (rwn != rwm)) ? -100.f : 0.f;
          sv[4 * mt + r] = sA[mt][r] * scale + bias + msk;
        }
      float mx = sv[0];
#pragma unroll
      for (int i = 1; i < 8; i++) mx = fmaxf(mx, sv[i]);
      mx = fmaxf(mx, __shfl_xor(mx, 16));
      mx = fmaxf(mx, __shfl_xor(mx, 32));
      float sum = 0.f;
#pragma unroll
      for (int i = 0; i < 8; i++) { sv[i] = __expf(sv[i] - mx); sum += sv[i]; }
      sum += __shfl_xor(sum, 16);
      sum += __shfl_xor(sum, 32);
      const float inv = 1.f / sum;
#pragma unroll
      for (int mt = 0; mt < 2; mt++) {
        uint2 w;
        w.x = pk2(sv[4 * mt] * inv,     sv[4 * mt + 1] * inv);
        w.y = pk2(sv[4 * mt + 2] * inv, sv[4 * mt + 3] * inv);
        *reinterpret_cast<uint2*>(&Pl[hh][qn][16 * mt + quad * 4]) = w;
      }
    }
    bar_lds();

    // ---- PV: O^T = V^T @ P^T. wave -> (head hh, dim-half qh) ----
    {
      const short8 a = lds16(&VT[hh * 32 + 16 * qh + col][quad * 8]);
#pragma unroll
      for (int nt = 0; nt < 2; nt++) {
        const short8 bb = lds16(&Pl[hh][16 * nt + col][quad * 8]);
        const f32x4 o = __builtin_amdgcn_mfma_f32_16x16x32_bf16(a, bb, zf, 0, 0, 0);
        uint2 w;
        w.x = pk2(o[0], o[1]);
        w.y = pk2(o[2], o[3]);
        *reinterpret_cast<uint2*>(&Ou[16 * nt + col][hg * 32 + 16 * qh + quad * 4]) = w;
      }
    }
    bar_lds();
  }

  // ---- proj GEMM (transposed): D[chan][tok]; + bias + residual -> out ----
  {
    f32x4 pacc[3][2];
#pragma unroll
    for (int mt = 0; mt < 3; mt++)
#pragma unroll
      for (int nt = 0; nt < 2; nt++) pacc[mt][nt] = zf;

#pragma unroll
    for (int ks = 0; ks < 6; ks++) {
      short8 of[2];
#pragma unroll
      for (int nt = 0; nt < 2; nt++)
        of[nt] = lds16(&Ou[16 * nt + col][ks * 32 + quad * 8]);
#pragma unroll
      for (int mt = 0; mt < 3; mt++)
#pragma unroll
        for (int nt = 0; nt < 2; nt++)
          pacc[mt][nt] = __builtin_amdgcn_mfma_f32_16x16x32_bf16(
              wreg[mt * 6 + ks], of[nt], pacc[mt][nt], 0, 0, 0);
    }

    size_t gb[2];
#pragma unroll
    for (int nt = 0; nt < 2; nt++)
      gb[nt] = (size_t)gtok(16 * nt + col) * 192;

#pragma unroll
    for (int mt = 0; mt < 3; mt++) {
      const int c0 = wave * 48 + 16 * mt + quad * 4;
      float bp[4];
#pragma unroll
      for (int r = 0; r < 4; r++) bp[r] = b2f(Pb[1216 + c0 + r]);
#pragma unroll
      for (int nt = 0; nt < 2; nt++) {
        const size_t gi = gb[nt] + c0;
        float f[4];
        ld4f(x, gi, bf, f);
#pragma unroll
        for (int r = 0; r < 4; r++) f[r] += pacc[mt][nt][r] + bp[r];
        st4f(out, gi, bf, f);
      }
    }
  }
}

// ---------------------------------------------------------------------------
// Kernel B: MLP, in-place on d_out. 64 tokens/block. Transposed GEMMs:
// GEMM1 D[j][tok] -> GELU lane holds 4 contiguous j -> packed uint2 X2 store;
// GEMM2 D[c][tok] -> epilogue lane holds 4 contiguous c -> float4/uint2 RMW.
// Hidden (768) in 6 chunks of 128. wreg[12] ping-pongs W1/W2 fragments.
// ---------------------------------------------------------------------------
__launch_bounds__(256, 3)
__global__ void swin_mlp_mfma(
    const u16* __restrict__ bff,
    void* __restrict__ io, const void* __restrict__ g2, const void* __restrict__ be2,
    const u16* __restrict__ w1t,   // [768][192] bf16
    const void* __restrict__ bm1,
    const u16* __restrict__ w2t,   // [192][768] bf16
    const void* __restrict__ bm2)
{
  __shared__ __align__(16) u16 Xn[64][200];   // LN2 out [tok][chan]  25600 B
  __shared__ __align__(16) u16 X2[64][136];   // gelu chunk [tok][j]  17408 B
  __shared__ u16 Pm[1344];  // bm1@0[768] bm2@768[192] g2@960[192] be2@1152[192]

  const bool bf = bff[0] != 0;
  const int tid = threadIdx.x;
  const size_t tok0 = (size_t)blockIdx.x * 64;
  const int wave = tid >> 6;
  const int lane = tid & 63;
  const int col  = lane & 15;
  const int quad = lane >> 4;

  // ---- stage params ----
#pragma unroll
  for (int i0 = 0; i0 < 6; i0++) {
    const int i = i0 * 256 + tid;
    if (i < 1344) {
      float vv;
      if (i < 768) vv = ld1(bm1, i, bf);
      else if (i < 960) vv = ld1(bm2, i - 768, bf);
      else if (i < 1152) vv = ld1(g2, i - 960, bf);
      else vv = ld1(be2, i - 1152, bf);
      Pm[i] = f2b(vv);
    }
  }

  // ---- LN2 loads, then W1(ch0) prefetch ----
  short8 wreg[12];
  float v[48];
  const int ln_t = tid >> 2, ln_g = tid & 3, ln_c0 = 48 * ln_g;
  {
    const size_t base = (tok0 + ln_t) * 192 + ln_c0;
#pragma unroll
    for (int i = 0; i < 6; i++) ld8(io, base + 8 * i, bf, v + 8 * i);
  }
  {
    const u16* wb = w1t + (size_t)(wave * 32 + col) * 192 + quad * 8;
#pragma unroll
    for (int mt = 0; mt < 2; mt++)
#pragma unroll
      for (int ks = 0; ks < 6; ks++)
        wreg[mt * 6 + ks] = gld16(wb + mt * 16 * 192 + ks * 32);
  }
  bar_lds();   // Pm visible

  // ---- LN2 compute -> Xn ----
  {
    float s = 0.f, ss = 0.f;
#pragma unroll
    for (int i = 0; i < 48; i++) { s += v[i]; ss += v[i] * v[i]; }
#pragma unroll
    for (int o = 1; o < 4; o <<= 1) { s += __shfl_xor(s, o); ss += __shfl_xor(ss, o); }
    const float mu = s * (1.f / 192.f);
    const float rstd = rsqrtf(ss * (1.f / 192.f) - mu * mu + 1e-5f);
    u32* dst = reinterpret_cast<u32*>(&Xn[ln_t][ln_c0]);
#pragma unroll
    for (int i = 0; i < 24; i++) {
      const int c = ln_c0 + 2 * i;
      const float r0 = (v[2*i]   - mu) * rstd * b2f(Pm[960 + c])     + b2f(Pm[1152 + c]);
      const float r1 = (v[2*i+1] - mu) * rstd * b2f(Pm[960 + c + 1]) + b2f(Pm[1152 + c + 1]);
      dst[i] = pk2(r0, r1);
    }
  }
  bar_lds();   // Xn visible

  f32x4 acc2[3][4];
#pragma unroll
  for (int mt = 0; mt < 3; mt++)
#pragma unroll
    for (int nt = 0; nt < 4; nt++) acc2[mt][nt] = (f32x4){0.f, 0.f, 0.f, 0.f};

  for (int ch = 0; ch < 6; ++ch) {
    // ---- GEMM1 (transposed): D[j][tok]; wave owns 32 j-rows ----
    f32x4 acc1[2][4];
#pragma unroll
    for (int mt = 0; mt < 2; mt++)
#pragma unroll
      for (int nt = 0; nt < 4; nt++) acc1[mt][nt] = (f32x4){0.f, 0.f, 0.f, 0.f};

#pragma unroll
    for (int ks = 0; ks < 6; ks++) {
      short8 xf[4];
#pragma unroll
      for (int nt = 0; nt < 4; nt++)
        xf[nt] = lds16(&Xn[16 * nt + col][ks * 32 + quad * 8]);
#pragma unroll
      for (int mt = 0; mt < 2; mt++)
#pragma unroll
        for (int nt = 0; nt < 4; nt++)
          acc1[mt][nt] = __builtin_amdgcn_mfma_f32_16x16x32_bf16(
              wreg[mt * 6 + ks], xf[nt], acc1[mt][nt], 0, 0, 0);
    }

    // ---- prefetch W2(ch) fragments (hide under GELU) ----
    {
#pragma unroll
      for (int mt = 0; mt < 3; mt++)
#pragma unroll
        for (int ks = 0; ks < 4; ks++)
          wreg[mt * 4 + ks] = gld16(w2t + (size_t)(wave * 48 + mt * 16 + col) * 768
                                         + ch * 128 + ks * 32 + quad * 8);
    }

    // ---- GELU + packed store chunk to X2[tok][j] ----
#pragma unroll
    for (int mt = 0; mt < 2; mt++) {
      const int j0 = wave * 32 + 16 * mt + quad * 4;   // 4 contiguous j
      float b1[4];
#pragma unroll
      for (int r = 0; r < 4; r++) b1[r] = b2f(Pm[ch * 128 + j0 + r]);
#pragma unroll
      for (int nt = 0; nt < 4; nt++) {
        const int tok = 16 * nt + col;
        uint2 w;
        w.x = pk2(gelu_t(acc1[mt][nt][0] + b1[0]), gelu_t(acc1[mt][nt][1] + b1[1]));
        w.y = pk2(gelu_t(acc1[mt][nt][2] + b1[2]), gelu_t(acc1[mt][nt][3] + b1[3]));
        *reinterpret_cast<uint2*>(&X2[tok][j0]) = w;
      }
    }
    bar_lds();

    // ---- GEMM2 partial (transposed): D[c][tok] += w2_chunk . gelu_chunk ----
#pragma unroll
    for (int ks = 0; ks < 4; ks++) {
      short8 xf2[4];
#pragma unroll
      for (int nt = 0; nt < 4; nt++)
        xf2[nt] = lds16(&X2[16 * nt + col][ks * 32 + quad * 8]);
#pragma unroll
      for (int mt = 0; mt < 3; mt++)
#pragma unroll
        for (int nt = 0; nt < 4; nt++)
          acc2[mt][nt] = __builtin_amdgcn_mfma_f32_16x16x32_bf16(
              wreg[mt * 4 + ks], xf2[nt], acc2[mt][nt], 0, 0, 0);
    }

    // ---- prefetch W1(ch+1) fragments ----
    if (ch < 5) {
      const u16* wb = w1t + (size_t)((ch + 1) * 128 + wave * 32 + col) * 192 + quad * 8;
#pragma unroll
      for (int mt = 0; mt < 2; mt++)
#pragma unroll
        for (int ks = 0; ks < 6; ks++)
          wreg[mt * 6 + ks] = gld16(wb + mt * 16 * 192 + ks * 32);
    }
    bar_lds();
  }

  // ---- epilogue: + bm2 + x1 residual, vectorized RMW (4 contiguous c) ----
#pragma unroll
  for (int mt = 0; mt < 3; mt++) {
    const int c0 = wave * 48 + 16 * mt + quad * 4;
    float b2[4];
#pragma unroll
    for (int r = 0; r < 4; r++) b2[r] = b2f(Pm[768 + c0 + r]);
#pragma unroll
    for (int nt = 0; nt < 4; nt++) {
      const int tok = 16 * nt + col;
      const size_t idx = (tok0 + tok) * 192 + c0;
      float f[4];
      ld4f(io, idx, bf, f);
#pragma unroll
      for (int r = 0; r < 4; r++) f[r] += acc2[mt][nt][r] + b2[r];
      st4f(io, idx, bf, f);
    }
  }
}

extern "C" void kernel_launch(void* const* d_in, const int* in_sizes, int n_in,
                              void* d_out, int out_size, void* d_ws, size_t ws_size,
                              hipStream_t stream) {
  const void* x     = d_in[0];
  const void* g1    = d_in[3];
  const void* be1   = d_in[4];
  const void* wqkv  = d_in[5];
  const void* bqkv  = d_in[6];
  const void* wproj = d_in[7];
  const void* bproj = d_in[8];
  const void* btab  = d_in[9];
  const void* g2    = d_in[10];
  const void* be2   = d_in[11];
  const void* w1    = d_in[12];
  const void* bm1   = d_in[13];
  const void* w2    = d_in[14];
  const void* bm2   = d_in[15];

  u16* ws = (u16*)d_ws;   // w1t @0, w2t @147456, wqkvT @294912, wprojT @405504, flag @442368

  // 1) transpose weights into ws + dtype flag
  transpose_weights<<<1728, 256, 0, stream>>>(w1, w2, wqkv, wproj, ws);
  // 2) attention (MFMA): one block per window, writes x1 into d_out
  swin_attn_mfma<<<8192, 256, 0, stream>>>(x, g1, be1, ws + 294912, bqkv,
                                           ws + 405504, bproj, btab,
                                           ws + FLAG_OFF, d_out);
  // 3) MLP (MFMA), in-place on d_out
  swin_mlp_mfma<<<4096, 256, 0, stream>>>(ws + FLAG_OFF, d_out, g2, be2,
                                          ws, bm1, ws + 147456, bm2);
}